// Round 1
// baseline (2866.772 us; speedup 1.0000x reference)
//
#include <hip/hip_runtime.h>
#include <math.h>

// Problem constants
constexpr int B_ = 2, S_ = 2048, D_ = 2048, H_ = 16, HD_ = 128, RANK_ = 512;
constexpr float EPS = 1e-6f;
constexpr float SCALE = 0.08838834764831845f; // 1/sqrt(128)

#define BQ 16
#define BKC 32

// ---------------------------------------------------------------------------
// GEMM NT: C[M,N] = A[M,K] @ W[N,K]^T   (fp32, 64x64 tile, BK=16, 4x4/thread)
// M,N,K all multiples of 64/16 in this problem -> no bounds checks.
// ---------------------------------------------------------------------------
__global__ __launch_bounds__(256) void gemm_nt(const float* __restrict__ A,
                                               const float* __restrict__ W,
                                               float* __restrict__ C,
                                               int M, int N, int K) {
    __shared__ float As[16][68]; // k-major, pad 68 (16B-aligned rows, low conflict)
    __shared__ float Ws[16][68];
    const int tid = threadIdx.x;
    const int tx = tid & 15, ty = tid >> 4;
    const int m0 = blockIdx.y * 64, n0 = blockIdx.x * 64;
    const int row = tid >> 2;        // 0..63
    const int kq  = (tid & 3) << 2;  // 0,4,8,12

    float acc[4][4] = {};

    for (int k0 = 0; k0 < K; k0 += 16) {
        float4 av = *(const float4*)&A[(size_t)(m0 + row) * K + k0 + kq];
        float4 wv = *(const float4*)&W[(size_t)(n0 + row) * K + k0 + kq];
        __syncthreads(); // previous compute done before overwrite
        As[kq + 0][row] = av.x; As[kq + 1][row] = av.y;
        As[kq + 2][row] = av.z; As[kq + 3][row] = av.w;
        Ws[kq + 0][row] = wv.x; Ws[kq + 1][row] = wv.y;
        Ws[kq + 2][row] = wv.z; Ws[kq + 3][row] = wv.w;
        __syncthreads();
#pragma unroll
        for (int k = 0; k < 16; k++) {
            float4 a = *(const float4*)&As[k][ty * 4];
            float4 w = *(const float4*)&Ws[k][tx * 4];
            float ar[4] = {a.x, a.y, a.z, a.w};
            float wr[4] = {w.x, w.y, w.z, w.w};
#pragma unroll
            for (int i = 0; i < 4; i++)
#pragma unroll
                for (int j = 0; j < 4; j++) acc[i][j] += ar[i] * wr[j];
        }
    }
#pragma unroll
    for (int i = 0; i < 4; i++) {
        float4 o = make_float4(acc[i][0], acc[i][1], acc[i][2], acc[i][3]);
        *(float4*)&C[(size_t)(m0 + ty * 4 + i) * N + n0 + tx * 4] = o;
    }
}

// ---------------------------------------------------------------------------
// In-place RMSNorm over rows of 512 (one block per row)
// ---------------------------------------------------------------------------
__global__ __launch_bounds__(256) void rmsnorm_rows(float* __restrict__ X,
                                                    const float* __restrict__ w) {
    const int row = blockIdx.x;
    float* x = X + (size_t)row * RANK_;
    const int t = threadIdx.x;
    float v0 = x[t], v1 = x[t + 256];
    float ss = v0 * v0 + v1 * v1;
#pragma unroll
    for (int off = 32; off; off >>= 1) ss += __shfl_down(ss, off);
    __shared__ float red[4];
    if ((t & 63) == 0) red[t >> 6] = ss;
    __syncthreads();
    float tot = red[0] + red[1] + red[2] + red[3];
    float rs = rsqrtf(tot * (1.0f / RANK_) + EPS);
    x[t]       = v0 * rs * w[t];
    x[t + 256] = v1 * rs * w[t + 256];
}

// ---------------------------------------------------------------------------
// V head-mix: v[t, i, d] = sum_j kron[i][j] * xt[t, j, d]   (one block/token)
// ---------------------------------------------------------------------------
__global__ __launch_bounds__(256) void vmix_kernel(const float* __restrict__ xt,
                                                   const float* __restrict__ kron,
                                                   float* __restrict__ V) {
    __shared__ float xr[2048];
    __shared__ float kr[256];
    const int bs = blockIdx.x;
    const float* x = xt + (size_t)bs * 2048;
    const int t = threadIdx.x;
    kr[t] = kron[t];
#pragma unroll
    for (int it = 0; it < 8; it++) xr[t + it * 256] = x[t + it * 256];
    __syncthreads();
    const int d = t & 127;
    const int i0 = (t >> 7) * 8;
    float acc[8] = {};
#pragma unroll
    for (int j = 0; j < 16; j++) {
        float xv = xr[j * 128 + d];
#pragma unroll
        for (int ii = 0; ii < 8; ii++) acc[ii] += kr[(i0 + ii) * 16 + j] * xv;
    }
    float* out = V + (size_t)bs * 2048;
#pragma unroll
    for (int ii = 0; ii < 8; ii++) out[(i0 + ii) * 128 + d] = acc[ii];
}

// ---------------------------------------------------------------------------
// Flash attention, fp32, ALiBi + causal. BQ=16 queries/block, BK=32 keys/chunk.
// 256 threads: r = tid>>4 (query row), g = tid&15.
//   scores: thread handles cols {g, g+16};  PV: thread owns dims d = g*8..g*8+7
// ---------------------------------------------------------------------------
__global__ __launch_bounds__(256) void flash_attn(const float* __restrict__ Q,
                                                  const float* __restrict__ Kt,
                                                  const float* __restrict__ Vt,
                                                  float* __restrict__ O) {
    __shared__ float q_lds[BQ][132];
    __shared__ float k_lds[BKC][132];
    __shared__ float v_lds[BKC][132];
    __shared__ float p_lds[BQ][BKC + 1];

    const int q0 = blockIdx.x * BQ;
    const int h  = blockIdx.y;
    const int b  = blockIdx.z;
    const int tid = threadIdx.x;
    const int r = tid >> 4, g = tid & 15;
    const size_t rs = (size_t)H_ * HD_; // token row stride = 2048

    const float* qb = Q + (size_t)b * S_ * rs + (size_t)h * HD_;
    const float* kb = Kt + (size_t)b * S_ * rs + (size_t)h * HD_;
    const float* vb = Vt + (size_t)b * S_ * rs + (size_t)h * HD_;

    // load Q tile (16 x 128 = 512 float4)
    {
        int idx = tid;
#pragma unroll
        for (int it = 0; it < 2; it++, idx += 256) {
            int rr = idx >> 5;
            int c4 = (idx & 31) << 2;
            *(float4*)&q_lds[rr][c4] = *(const float4*)&qb[(size_t)(q0 + rr) * rs + c4];
        }
    }

    const float slope = exp2f(-0.5f * (float)(h + 1));
    float m_i = -INFINITY, l_i = 0.f;
    float acc[8] = {};
    const int q_pos = q0 + r;
    const int nchunk = (q0 + BQ + BKC - 1) / BKC;

    for (int ch = 0; ch < nchunk; ch++) {
        const int k0 = ch * BKC;
        __syncthreads(); // prev PV done before K/V overwrite
        {
            int idx = tid;
#pragma unroll
            for (int it = 0; it < 4; it++, idx += 256) {
                int rr = idx >> 5;
                int c4 = (idx & 31) << 2;
                *(float4*)&k_lds[rr][c4] = *(const float4*)&kb[(size_t)(k0 + rr) * rs + c4];
                *(float4*)&v_lds[rr][c4] = *(const float4*)&vb[(size_t)(k0 + rr) * rs + c4];
            }
        }
        __syncthreads();

        float sc[2];
#pragma unroll
        for (int j = 0; j < 2; j++) {
            const int c = g + 16 * j;
            const float4* qr = (const float4*)&q_lds[r][0];
            const float4* krow = (const float4*)&k_lds[c][0];
            float a = 0.f;
#pragma unroll
            for (int kk = 0; kk < 32; kk++) {
                float4 qv = qr[kk], kv = krow[kk];
                a += qv.x * kv.x + qv.y * kv.y + qv.z * kv.z + qv.w * kv.w;
            }
            const int k_pos = k0 + c;
            sc[j] = (k_pos <= q_pos)
                        ? (a * SCALE + slope * (float)(k_pos - q_pos))
                        : -INFINITY;
        }
        float cmax = fmaxf(sc[0], sc[1]);
#pragma unroll
        for (int off = 8; off; off >>= 1) cmax = fmaxf(cmax, __shfl_xor(cmax, off));
        const float m_new = fmaxf(m_i, cmax);
        const float alpha = expf(m_i - m_new); // expf(-inf)=0 on first chunk
        float psum = 0.f;
#pragma unroll
        for (int j = 0; j < 2; j++) {
            float p = expf(sc[j] - m_new);
            p_lds[r][g + 16 * j] = p;
            psum += p;
        }
#pragma unroll
        for (int off = 8; off; off >>= 1) psum += __shfl_xor(psum, off);
        l_i = l_i * alpha + psum;
        m_i = m_new;
#pragma unroll
        for (int ii = 0; ii < 8; ii++) acc[ii] *= alpha;
        __syncthreads(); // p_lds visible; K/V load complete

#pragma unroll 4
        for (int c = 0; c < BKC; c++) {
            const float p = p_lds[r][c];
            const float4* vr = (const float4*)&v_lds[c][g * 8];
            float4 v0 = vr[0], v1 = vr[1];
            acc[0] += p * v0.x; acc[1] += p * v0.y;
            acc[2] += p * v0.z; acc[3] += p * v0.w;
            acc[4] += p * v1.x; acc[5] += p * v1.y;
            acc[6] += p * v1.z; acc[7] += p * v1.w;
        }
    }

    const float inv = 1.0f / l_i;
    float* ob = O + ((size_t)b * S_ + q0 + r) * rs + (size_t)h * HD_ + g * 8;
    *(float4*)&ob[0] = make_float4(acc[0] * inv, acc[1] * inv, acc[2] * inv, acc[3] * inv);
    *(float4*)&ob[4] = make_float4(acc[4] * inv, acc[5] * inv, acc[6] * inv, acc[7] * inv);
}

// ---------------------------------------------------------------------------
extern "C" void kernel_launch(void* const* d_in, const int* in_sizes, int n_in,
                              void* d_out, int out_size, void* d_ws, size_t ws_size,
                              hipStream_t stream) {
    const float* x    = (const float*)d_in[0]; // [B,S,D]
    const float* xt   = (const float*)d_in[1]; // [B,S,D]
    const float* wq   = (const float*)d_in[2]; // [2048,2048]
    const float* wka  = (const float*)d_in[3]; // [512,2048]
    const float* knw  = (const float*)d_in[4]; // [512]
    const float* wkb  = (const float*)d_in[5]; // [2048,512]
    const float* kron = (const float*)d_in[6]; // [16,16]
    const float* wo   = (const float*)d_in[7]; // [2048,2048]
    float* out = (float*)d_out;

    const int M = B_ * S_; // 4096 tokens
    float* ws = (float*)d_ws;
    float* q   = ws;                        // M*2048
    float* k   = q + (size_t)M * 2048;      // M*2048
    float* v   = k + (size_t)M * 2048;      // M*2048
    float* att = v + (size_t)M * 2048;      // M*2048
    float* kc  = att;                       // M*512 (dead before att is written)

    // Q = x @ wq^T
    gemm_nt<<<dim3(2048 / 64, M / 64), 256, 0, stream>>>(x, wq, q, M, 2048, 2048);
    // kc = x @ wka^T ; RMSNorm in place
    gemm_nt<<<dim3(512 / 64, M / 64), 256, 0, stream>>>(x, wka, kc, M, 512, 2048);
    rmsnorm_rows<<<M, 256, 0, stream>>>(kc, knw);
    // K = kc @ wkb^T
    gemm_nt<<<dim3(2048 / 64, M / 64), 256, 0, stream>>>(kc, wkb, k, M, 2048, 512);
    // V = kron head-mix of xt
    vmix_kernel<<<M, 256, 0, stream>>>(xt, kron, v);
    // attention
    flash_attn<<<dim3(S_ / BQ, H_, B_), 256, 0, stream>>>(q, k, v, att);
    // out = att @ wo^T
    gemm_nt<<<dim3(2048 / 64, M / 64), 256, 0, stream>>>(att, wo, out, M, 2048, 2048);
}

// Round 2
// 1569.480 us; speedup vs baseline: 1.8266x; 1.8266x over previous
//
#include <hip/hip_runtime.h>
#include <math.h>

// Problem constants
constexpr int B_ = 2, S_ = 2048, D_ = 2048, H_ = 16, HD_ = 128, RANK_ = 512;
constexpr float EPS = 1e-6f;
constexpr float SCALE = 0.08838834764831845f; // 1/sqrt(128)

typedef __attribute__((ext_vector_type(8))) short bfrag8; // 8 bf16 (4 VGPRs)
typedef __attribute__((ext_vector_type(4))) float f32x4;  // MFMA C/D

static __device__ __forceinline__ short f2bf(float f) {
    union { float f; unsigned u; } v; v.f = f;
    unsigned r = v.u + 0x7fffu + ((v.u >> 16) & 1u); // RNE
    return (short)(r >> 16);
}

// ---------------------------------------------------------------------------
// GEMM NT: C[M,N] = A[M,K] @ W[N,K]^T   (fp32, 64x64 tile, BK=16, 4x4/thread)
// ---------------------------------------------------------------------------
__global__ __launch_bounds__(256) void gemm_nt(const float* __restrict__ A,
                                               const float* __restrict__ W,
                                               float* __restrict__ C,
                                               int M, int N, int K) {
    __shared__ float As[16][68];
    __shared__ float Ws[16][68];
    const int tid = threadIdx.x;
    const int tx = tid & 15, ty = tid >> 4;
    const int m0 = blockIdx.y * 64, n0 = blockIdx.x * 64;
    const int row = tid >> 2;
    const int kq  = (tid & 3) << 2;

    float acc[4][4] = {};

    for (int k0 = 0; k0 < K; k0 += 16) {
        float4 av = *(const float4*)&A[(size_t)(m0 + row) * K + k0 + kq];
        float4 wv = *(const float4*)&W[(size_t)(n0 + row) * K + k0 + kq];
        __syncthreads();
        As[kq + 0][row] = av.x; As[kq + 1][row] = av.y;
        As[kq + 2][row] = av.z; As[kq + 3][row] = av.w;
        Ws[kq + 0][row] = wv.x; Ws[kq + 1][row] = wv.y;
        Ws[kq + 2][row] = wv.z; Ws[kq + 3][row] = wv.w;
        __syncthreads();
#pragma unroll
        for (int k = 0; k < 16; k++) {
            float4 a = *(const float4*)&As[k][ty * 4];
            float4 w = *(const float4*)&Ws[k][tx * 4];
            float ar[4] = {a.x, a.y, a.z, a.w};
            float wr[4] = {w.x, w.y, w.z, w.w};
#pragma unroll
            for (int i = 0; i < 4; i++)
#pragma unroll
                for (int j = 0; j < 4; j++) acc[i][j] += ar[i] * wr[j];
        }
    }
#pragma unroll
    for (int i = 0; i < 4; i++) {
        float4 o = make_float4(acc[i][0], acc[i][1], acc[i][2], acc[i][3]);
        *(float4*)&C[(size_t)(m0 + ty * 4 + i) * N + n0 + tx * 4] = o;
    }
}

// ---------------------------------------------------------------------------
// In-place RMSNorm over rows of 512
// ---------------------------------------------------------------------------
__global__ __launch_bounds__(256) void rmsnorm_rows(float* __restrict__ X,
                                                    const float* __restrict__ w) {
    const int row = blockIdx.x;
    float* x = X + (size_t)row * RANK_;
    const int t = threadIdx.x;
    float v0 = x[t], v1 = x[t + 256];
    float ss = v0 * v0 + v1 * v1;
#pragma unroll
    for (int off = 32; off; off >>= 1) ss += __shfl_down(ss, off);
    __shared__ float red[4];
    if ((t & 63) == 0) red[t >> 6] = ss;
    __syncthreads();
    float tot = red[0] + red[1] + red[2] + red[3];
    float rs = rsqrtf(tot * (1.0f / RANK_) + EPS);
    x[t]       = v0 * rs * w[t];
    x[t + 256] = v1 * rs * w[t + 256];
}

// ---------------------------------------------------------------------------
// V head-mix: v[t, i, d] = sum_j kron[i][j] * xt[t, j, d]
// ---------------------------------------------------------------------------
__global__ __launch_bounds__(256) void vmix_kernel(const float* __restrict__ xt,
                                                   const float* __restrict__ kron,
                                                   float* __restrict__ V) {
    __shared__ float xr[2048];
    __shared__ float kr[256];
    const int bs = blockIdx.x;
    const float* x = xt + (size_t)bs * 2048;
    const int t = threadIdx.x;
    kr[t] = kron[t];
#pragma unroll
    for (int it = 0; it < 8; it++) xr[t + it * 256] = x[t + it * 256];
    __syncthreads();
    const int d = t & 127;
    const int i0 = (t >> 7) * 8;
    float acc[8] = {};
#pragma unroll
    for (int j = 0; j < 16; j++) {
        float xv = xr[j * 128 + d];
#pragma unroll
        for (int ii = 0; ii < 8; ii++) acc[ii] += kr[(i0 + ii) * 16 + j] * xv;
    }
    float* out = V + (size_t)bs * 2048;
#pragma unroll
    for (int ii = 0; ii < 8; ii++) out[(i0 + ii) * 128 + d] = acc[ii];
}

// ---------------------------------------------------------------------------
// MFMA flash attention (bf16 QK^T / PV, fp32 softmax + accum).
// Block = 256 threads = 4 waves. BQ=64 (16 q-rows per wave), BK=32 keys/chunk.
// K chunk + transposed V chunk staged in LDS (shared); P buffer per-wave.
// mfma_f32_16x16x32_bf16 layouts (HW-verified per guide):
//   A: A[m=lane&15][k=quad*8+j]   B: B[k=quad*8+j][n=lane&15]
//   C/D: row=quad*4+reg, col=lane&15
// ---------------------------------------------------------------------------
constexpr int QST = 128; // q_s row stride (shorts) — read once, conflicts don't matter
constexpr int KST = 136; // k_s row stride — 272B rows: b128 reads 2-way (free)
constexpr int VST = 40;  // vt_s row stride
constexpr int PST = 40;  // p_s row stride

__global__ __launch_bounds__(256, 4)
void flash_mfma(const float* __restrict__ Q, const float* __restrict__ K,
                const float* __restrict__ V, float* __restrict__ O) {
    __shared__ __align__(16) short q_s[64 * QST];   // 16384 B
    __shared__ __align__(16) short k_s[32 * KST];   //  8704 B
    __shared__ __align__(16) short vt_s[128 * VST]; // 10240 B
    __shared__ __align__(16) short p_s[4][16 * PST];//  5120 B  => 40448 B total

    const int tid = threadIdx.x;
    const int wave = tid >> 6, lane = tid & 63;
    const int quad = lane >> 4, l16 = lane & 15;
    const int q0 = blockIdx.x * 64;
    const int h = blockIdx.y, b = blockIdx.z;
    const size_t tokb = (size_t)b * S_;
    const size_t hoff = (size_t)h * HD_;

    const float* qg = Q + (tokb + q0) * 2048 + hoff;
    const float* kg = K + tokb * 2048 + hoff;
    const float* vg = V + tokb * 2048 + hoff;

    // ---- stage Q tile (64 x 128) as bf16 ----
    {
        const int row = tid >> 2, c0 = (tid & 3) * 32;
        const float* src = qg + (size_t)row * 2048 + c0;
        short* dst = &q_s[row * QST + c0];
#pragma unroll
        for (int j = 0; j < 8; j++) {
            float4 fv = *(const float4*)&src[j * 4];
            short4 s;
            s.x = f2bf(fv.x); s.y = f2bf(fv.y); s.z = f2bf(fv.z); s.w = f2bf(fv.w);
            *(short4*)&dst[j * 4] = s;
        }
    }
    __syncthreads();

    // hoisted Q A-frags (Q never changes)
    bfrag8 aq[4];
#pragma unroll
    for (int kb = 0; kb < 4; kb++)
        aq[kb] = *(const bfrag8*)&q_s[(wave * 16 + l16) * QST + kb * 32 + quad * 8];

    const float slope = exp2f(-0.5f * (float)(h + 1));
    float m_i[4] = {-INFINITY, -INFINITY, -INFINITY, -INFINITY};
    float l_i[4] = {0.f, 0.f, 0.f, 0.f};
    f32x4 o[8];
#pragma unroll
    for (int t = 0; t < 8; t++) o[t] = (f32x4){0.f, 0.f, 0.f, 0.f};

    const int q_pos0 = q0 + wave * 16 + quad * 4; // + r
    const int nch = q0 / 32 + 2;
    // Vt staging: key stored at slot (key + ((d>>4)&3)*8) & 31 (2-way writes)
    const int kslot = ((tid >> 3) + (tid & 3) * 8) & 31;

    for (int ch = 0; ch < nch; ch++) {
        const int k0 = ch * 32;
        // ---- stage K (row layout) + V (transposed, slot-rotated) ----
        {
            const int row = tid >> 3, c0 = (tid & 7) * 16;
            const float* ks = kg + (size_t)(k0 + row) * 2048 + c0;
            short* kd = &k_s[row * KST + c0];
#pragma unroll
            for (int j = 0; j < 4; j++) {
                float4 fv = *(const float4*)&ks[j * 4];
                short4 s;
                s.x = f2bf(fv.x); s.y = f2bf(fv.y); s.z = f2bf(fv.z); s.w = f2bf(fv.w);
                *(short4*)&kd[j * 4] = s;
            }
            const float* vs = vg + (size_t)(k0 + row) * 2048 + c0;
#pragma unroll
            for (int j = 0; j < 16; j += 4) {
                float4 fv = *(const float4*)&vs[j];
                const int d = c0 + j;
                vt_s[(d + 0) * VST + kslot] = f2bf(fv.x);
                vt_s[(d + 1) * VST + kslot] = f2bf(fv.y);
                vt_s[(d + 2) * VST + kslot] = f2bf(fv.z);
                vt_s[(d + 3) * VST + kslot] = f2bf(fv.w);
            }
        }
        __syncthreads();

        // ---- QK^T: S[16q x 32keys] = two 16x16 MFMA tiles over 4 k-blocks ----
        f32x4 sc[2];
#pragma unroll
        for (int t = 0; t < 2; t++) {
            sc[t] = (f32x4){0.f, 0.f, 0.f, 0.f};
#pragma unroll
            for (int kb = 0; kb < 4; kb++) {
                bfrag8 bk = *(const bfrag8*)&k_s[(t * 16 + l16) * KST + kb * 32 + quad * 8];
                sc[t] = __builtin_amdgcn_mfma_f32_16x16x32_bf16(aq[kb], bk, sc[t], 0, 0, 0);
            }
        }

        // ---- bias + causal mask + online softmax (registers + shfl only) ----
        float p0v[4], p1v[4];
#pragma unroll
        for (int r = 0; r < 4; r++) {
            const int q_pos = q_pos0 + r;
            const int kp0 = k0 + l16, kp1 = k0 + 16 + l16;
            float s0 = sc[0][r] * SCALE + slope * (float)(kp0 - q_pos);
            float s1 = sc[1][r] * SCALE + slope * (float)(kp1 - q_pos);
            if (kp0 > q_pos) s0 = -INFINITY;
            if (kp1 > q_pos) s1 = -INFINITY;
            p0v[r] = s0; p1v[r] = s1;
            float m = fmaxf(s0, s1);
#pragma unroll
            for (int off = 8; off >= 1; off >>= 1) m = fmaxf(m, __shfl_xor(m, off));
            const float m_new = fmaxf(m_i[r], m);
            const float alpha = __expf(m_i[r] - m_new);
            m_i[r] = m_new;
            const float p0 = __expf(s0 - m_new);
            const float p1 = __expf(s1 - m_new);
            p0v[r] = p0; p1v[r] = p1;
            float rsum = p0 + p1;
#pragma unroll
            for (int off = 8; off >= 1; off >>= 1) rsum += __shfl_xor(rsum, off);
            l_i[r] = l_i[r] * alpha + rsum;
#pragma unroll
            for (int t = 0; t < 8; t++) o[t][r] *= alpha;
            const int qr = quad * 4 + r;
            p_s[wave][qr * PST + l16]      = f2bf(p0);
            p_s[wave][qr * PST + 16 + l16] = f2bf(p1);
        }

        // ---- PV: O[16q x 128d] += P[16x32] @ V[32xd]  (8 d-tiles) ----
        // p_s is wave-private; DS ops in-order within a wave -> no barrier needed.
        bfrag8 pa = *(const bfrag8*)&p_s[wave][l16 * PST + quad * 8];
#pragma unroll
        for (int t8 = 0; t8 < 8; t8++) {
            bfrag8 bv = *(const bfrag8*)&vt_s[(t8 * 16 + l16) * VST + ((quad + t8) & 3) * 8];
            o[t8] = __builtin_amdgcn_mfma_f32_16x16x32_bf16(pa, bv, o[t8], 0, 0, 0);
        }
        __syncthreads(); // all waves done reading k_s/vt_s before next stage
    }

    // ---- epilogue ----
    float inv[4];
#pragma unroll
    for (int r = 0; r < 4; r++) inv[r] = 1.0f / l_i[r];
    float* ob = O + (tokb + q0 + wave * 16 + quad * 4) * 2048 + hoff;
#pragma unroll
    for (int t8 = 0; t8 < 8; t8++)
#pragma unroll
        for (int r = 0; r < 4; r++)
            ob[(size_t)r * 2048 + t8 * 16 + l16] = o[t8][r] * inv[r];
}

// ---------------------------------------------------------------------------
extern "C" void kernel_launch(void* const* d_in, const int* in_sizes, int n_in,
                              void* d_out, int out_size, void* d_ws, size_t ws_size,
                              hipStream_t stream) {
    const float* x    = (const float*)d_in[0];
    const float* xt   = (const float*)d_in[1];
    const float* wq   = (const float*)d_in[2];
    const float* wka  = (const float*)d_in[3];
    const float* knw  = (const float*)d_in[4];
    const float* wkb  = (const float*)d_in[5];
    const float* kron = (const float*)d_in[6];
    const float* wo   = (const float*)d_in[7];
    float* out = (float*)d_out;

    const int M = B_ * S_;
    float* ws = (float*)d_ws;
    float* q   = ws;
    float* k   = q + (size_t)M * 2048;
    float* v   = k + (size_t)M * 2048;
    float* att = v + (size_t)M * 2048;
    float* kc  = att; // dead before att is written

    gemm_nt<<<dim3(2048 / 64, M / 64), 256, 0, stream>>>(x, wq, q, M, 2048, 2048);
    gemm_nt<<<dim3(512 / 64, M / 64), 256, 0, stream>>>(x, wka, kc, M, 512, 2048);
    rmsnorm_rows<<<M, 256, 0, stream>>>(kc, knw);
    gemm_nt<<<dim3(2048 / 64, M / 64), 256, 0, stream>>>(kc, wkb, k, M, 2048, 512);
    vmix_kernel<<<M, 256, 0, stream>>>(xt, kron, v);
    flash_mfma<<<dim3(S_ / 64, H_, B_), 256, 0, stream>>>(q, k, v, att);
    gemm_nt<<<dim3(2048 / 64, M / 64), 256, 0, stream>>>(att, wo, out, M, 2048, 2048);
}

// Round 3
// 599.855 us; speedup vs baseline: 4.7791x; 2.6164x over previous
//
#include <hip/hip_runtime.h>
#include <math.h>

// Problem constants
constexpr int B_ = 2, S_ = 2048, H_ = 16, HD_ = 128, RANK_ = 512;
constexpr float EPS = 1e-6f;
constexpr float SCALE = 0.08838834764831845f; // 1/sqrt(128)

typedef __attribute__((ext_vector_type(8))) short bfrag8; // 8 bf16 (4 VGPRs)
typedef __attribute__((ext_vector_type(4))) float f32x4;  // MFMA C/D

static __device__ __forceinline__ short f2bf(float f) {
    union { float f; unsigned u; } v; v.f = f;
    unsigned r = v.u + 0x7fffu + ((v.u >> 16) & 1u); // RNE
    return (short)(r >> 16);
}
static __device__ __forceinline__ float bf2f(short h) {
    union { unsigned u; float f; } v;
    v.u = ((unsigned)(unsigned short)h) << 16;
    return v.f;
}

typedef __attribute__((address_space(1))) void gvoid_t;
typedef __attribute__((address_space(3))) void lvoid_t;
// async global->LDS, 16 B/lane; LDS dest = wave-uniform base + lane*16
static __device__ __forceinline__ void gll16(const short* g, short* l) {
    __builtin_amdgcn_global_load_lds((const gvoid_t*)g, (lvoid_t*)l, 16, 0, 0);
}

// ---------------------------------------------------------------------------
// fp32 -> bf16 convert (n multiple of 2048; 8 elems/thread)
// ---------------------------------------------------------------------------
__global__ __launch_bounds__(256) void cvt_bf16(const float* __restrict__ in,
                                                short* __restrict__ out) {
    const int i = (blockIdx.x * 256 + threadIdx.x) * 8;
    float4 f0 = *(const float4*)&in[i];
    float4 f1 = *(const float4*)&in[i + 4];
    short s[8] = {f2bf(f0.x), f2bf(f0.y), f2bf(f0.z), f2bf(f0.w),
                  f2bf(f1.x), f2bf(f1.y), f2bf(f1.z), f2bf(f1.w)};
    *(int4*)&out[i] = *(const int4*)s;
}

// fp32 -> (hi, lo) bf16 split
__global__ __launch_bounds__(256) void cvt_split(const float* __restrict__ in,
                                                 short* __restrict__ hi,
                                                 short* __restrict__ lo) {
    const int i = (blockIdx.x * 256 + threadIdx.x) * 8;
    float f[8];
    *(float4*)&f[0] = *(const float4*)&in[i];
    *(float4*)&f[4] = *(const float4*)&in[i + 4];
    short h[8], l[8];
#pragma unroll
    for (int k = 0; k < 8; k++) {
        h[k] = f2bf(f[k]);
        l[k] = f2bf(f[k] - bf2f(h[k]));
    }
    *(int4*)&hi[i] = *(const int4*)h;
    *(int4*)&lo[i] = *(const int4*)l;
}

// ---------------------------------------------------------------------------
// bf16 MFMA GEMM (m97 structure): C[M,N] = A[M,K] @ W[N,K]^T
// 128x128 tile, BK=32, 256 thr = 4 waves (2x2 of 64x64), global_load_lds w=16.
// LDS tiles row-major unpadded (required by global_load_lds lane-contiguity).
// OUTBF: 1 -> bf16 C, 0 -> fp32 C.
// ---------------------------------------------------------------------------
template <int OUTBF>
__global__ __launch_bounds__(256)
void gemm_bf16(const short* __restrict__ A, const short* __restrict__ W,
               float* __restrict__ Cf, short* __restrict__ Cb,
               int M, int N, int K) {
    __shared__ short As[128 * 32]; // 8 KB, row stride 32 (64 B)
    __shared__ short Bs[128 * 32];
    const int tid = threadIdx.x;
    const int wave = tid >> 6, lane = tid & 63;
    const int quad = lane >> 4, l16 = lane & 15;
    const int wm = (wave & 1) * 64, wn = (wave >> 1) * 64;
    const int m0 = blockIdx.y * 128, n0 = blockIdx.x * 128;

    // staging: each wave covers 32 rows of each tile via 2 insts (16 rows/inst)
    const int srow = wave * 32 + (lane >> 2);
    const int scol = (lane & 3) * 8; // elem offset, 16 B granule
    const short* ag0 = A + (size_t)(m0 + srow) * K + scol;
    const short* ag1 = A + (size_t)(m0 + srow + 16) * K + scol;
    const short* bg0 = W + (size_t)(n0 + srow) * K + scol;
    const short* bg1 = W + (size_t)(n0 + srow + 16) * K + scol;
    short* al0 = &As[(wave * 32) * 32];
    short* al1 = &As[(wave * 32 + 16) * 32];
    short* bl0 = &Bs[(wave * 32) * 32];
    short* bl1 = &Bs[(wave * 32 + 16) * 32];

    f32x4 acc[4][4];
#pragma unroll
    for (int i = 0; i < 4; i++)
#pragma unroll
        for (int j = 0; j < 4; j++) acc[i][j] = (f32x4){0.f, 0.f, 0.f, 0.f};

    for (int k0 = 0; k0 < K; k0 += 32) {
        gll16(ag0 + k0, al0);
        gll16(ag1 + k0, al1);
        gll16(bg0 + k0, bl0);
        gll16(bg1 + k0, bl1);
        __syncthreads(); // drains vmcnt -> tiles visible
        bfrag8 af[4], bf[4];
#pragma unroll
        for (int i = 0; i < 4; i++)
            af[i] = *(const bfrag8*)&As[(wm + i * 16 + l16) * 32 + quad * 8];
#pragma unroll
        for (int j = 0; j < 4; j++)
            bf[j] = *(const bfrag8*)&Bs[(wn + j * 16 + l16) * 32 + quad * 8];
#pragma unroll
        for (int i = 0; i < 4; i++)
#pragma unroll
            for (int j = 0; j < 4; j++)
                acc[i][j] = __builtin_amdgcn_mfma_f32_16x16x32_bf16(af[i], bf[j], acc[i][j], 0, 0, 0);
        __syncthreads(); // all reads done before next stage overwrites
    }

#pragma unroll
    for (int i = 0; i < 4; i++)
#pragma unroll
        for (int j = 0; j < 4; j++) {
            const size_t rbase = (size_t)(m0 + wm + i * 16 + quad * 4);
            const int col = n0 + wn + j * 16 + l16;
#pragma unroll
            for (int r = 0; r < 4; r++) {
                if (OUTBF) Cb[(rbase + r) * N + col] = f2bf(acc[i][j][r]);
                else       Cf[(rbase + r) * N + col] = acc[i][j][r];
            }
        }
}

// ---------------------------------------------------------------------------
// split hi/lo 3-pass bf16 GEMM: C = (Ah+Al) @ (Wh+Wl)^T, drops Al*Wl (~2^-18)
// ---------------------------------------------------------------------------
__global__ __launch_bounds__(256)
void gemm_split3(const short* __restrict__ Ah, const short* __restrict__ Al,
                 const short* __restrict__ Wh, const short* __restrict__ Wl,
                 float* __restrict__ C, int M, int N, int K) {
    __shared__ short AsH[128 * 32], AsL[128 * 32];
    __shared__ short BsH[128 * 32], BsL[128 * 32]; // 32 KB total
    const int tid = threadIdx.x;
    const int wave = tid >> 6, lane = tid & 63;
    const int quad = lane >> 4, l16 = lane & 15;
    const int wm = (wave & 1) * 64, wn = (wave >> 1) * 64;
    const int m0 = blockIdx.y * 128, n0 = blockIdx.x * 128;

    const int srow = wave * 32 + (lane >> 2);
    const int scol = (lane & 3) * 8;
    const size_t aoff0 = (size_t)(m0 + srow) * K + scol;
    const size_t aoff1 = (size_t)(m0 + srow + 16) * K + scol;
    const size_t boff0 = (size_t)(n0 + srow) * K + scol;
    const size_t boff1 = (size_t)(n0 + srow + 16) * K + scol;
    short* lds0 = (short*)nullptr;
    const int lb0 = (wave * 32) * 32, lb1 = (wave * 32 + 16) * 32;

    f32x4 acc[4][4];
#pragma unroll
    for (int i = 0; i < 4; i++)
#pragma unroll
        for (int j = 0; j < 4; j++) acc[i][j] = (f32x4){0.f, 0.f, 0.f, 0.f};

    for (int k0 = 0; k0 < K; k0 += 32) {
        gll16(Ah + aoff0 + k0, &AsH[lb0]);
        gll16(Ah + aoff1 + k0, &AsH[lb1]);
        gll16(Al + aoff0 + k0, &AsL[lb0]);
        gll16(Al + aoff1 + k0, &AsL[lb1]);
        gll16(Wh + boff0 + k0, &BsH[lb0]);
        gll16(Wh + boff1 + k0, &BsH[lb1]);
        gll16(Wl + boff0 + k0, &BsL[lb0]);
        gll16(Wl + boff1 + k0, &BsL[lb1]);
        __syncthreads();
        bfrag8 fah[4], fal[4], fbh[4], fbl[4];
#pragma unroll
        for (int i = 0; i < 4; i++) {
            const int ro = (wm + i * 16 + l16) * 32 + quad * 8;
            fah[i] = *(const bfrag8*)&AsH[ro];
            fal[i] = *(const bfrag8*)&AsL[ro];
        }
#pragma unroll
        for (int j = 0; j < 4; j++) {
            const int ro = (wn + j * 16 + l16) * 32 + quad * 8;
            fbh[j] = *(const bfrag8*)&BsH[ro];
            fbl[j] = *(const bfrag8*)&BsL[ro];
        }
#pragma unroll
        for (int i = 0; i < 4; i++)
#pragma unroll
            for (int j = 0; j < 4; j++) {
                acc[i][j] = __builtin_amdgcn_mfma_f32_16x16x32_bf16(fah[i], fbh[j], acc[i][j], 0, 0, 0);
                acc[i][j] = __builtin_amdgcn_mfma_f32_16x16x32_bf16(fah[i], fbl[j], acc[i][j], 0, 0, 0);
                acc[i][j] = __builtin_amdgcn_mfma_f32_16x16x32_bf16(fal[i], fbh[j], acc[i][j], 0, 0, 0);
            }
        __syncthreads();
    }
    (void)lds0;

#pragma unroll
    for (int i = 0; i < 4; i++)
#pragma unroll
        for (int j = 0; j < 4; j++) {
            const size_t rbase = (size_t)(m0 + wm + i * 16 + quad * 4);
            const int col = n0 + wn + j * 16 + l16;
#pragma unroll
            for (int r = 0; r < 4; r++)
                C[(rbase + r) * N + col] = acc[i][j][r];
        }
}

// ---------------------------------------------------------------------------
// RMSNorm rows of 512: fp32 in -> bf16 out
// ---------------------------------------------------------------------------
__global__ __launch_bounds__(256) void rmsnorm_bf16(const float* __restrict__ X,
                                                    const float* __restrict__ w,
                                                    short* __restrict__ Y) {
    const int row = blockIdx.x;
    const float* x = X + (size_t)row * RANK_;
    const int t = threadIdx.x;
    float v0 = x[t], v1 = x[t + 256];
    float ss = v0 * v0 + v1 * v1;
#pragma unroll
    for (int off = 32; off; off >>= 1) ss += __shfl_down(ss, off);
    __shared__ float red[4];
    if ((t & 63) == 0) red[t >> 6] = ss;
    __syncthreads();
    float tot = red[0] + red[1] + red[2] + red[3];
    float rs = rsqrtf(tot * (1.0f / RANK_) + EPS);
    short* y = Y + (size_t)row * RANK_;
    y[t]       = f2bf(v0 * rs * w[t]);
    y[t + 256] = f2bf(v1 * rs * w[t + 256]);
}

// ---------------------------------------------------------------------------
// V head-mix -> bf16
// ---------------------------------------------------------------------------
__global__ __launch_bounds__(256) void vmix_kernel(const float* __restrict__ xt,
                                                   const float* __restrict__ kron,
                                                   short* __restrict__ V) {
    __shared__ float xr[2048];
    __shared__ float kr[256];
    const int bs = blockIdx.x;
    const float* x = xt + (size_t)bs * 2048;
    const int t = threadIdx.x;
    kr[t] = kron[t];
#pragma unroll
    for (int it = 0; it < 8; it++) xr[t + it * 256] = x[t + it * 256];
    __syncthreads();
    const int d = t & 127;
    const int i0 = (t >> 7) * 8;
    float acc[8] = {};
#pragma unroll
    for (int j = 0; j < 16; j++) {
        float xv = xr[j * 128 + d];
#pragma unroll
        for (int ii = 0; ii < 8; ii++) acc[ii] += kr[(i0 + ii) * 16 + j] * xv;
    }
    short* out = V + (size_t)bs * 2048;
#pragma unroll
    for (int ii = 0; ii < 8; ii++) out[(i0 + ii) * 128 + d] = f2bf(acc[ii]);
}

// ---------------------------------------------------------------------------
// MFMA flash attention: bf16 q/k/v in, (att_hi, att_lo) bf16 out.
// Block = 4 waves, BQ=64 (16 q-rows/wave), BK=32.
// ---------------------------------------------------------------------------
constexpr int QST = 128;
constexpr int KST = 136;
constexpr int VST = 40;
constexpr int PST = 40;

__global__ __launch_bounds__(256, 4)
void flash_mfma(const short* __restrict__ Q, const short* __restrict__ K,
                const short* __restrict__ V, short* __restrict__ Oh,
                short* __restrict__ Ol) {
    __shared__ __align__(16) short q_s[64 * QST];
    __shared__ __align__(16) short k_s[32 * KST];
    __shared__ __align__(16) short vt_s[128 * VST];
    __shared__ __align__(16) short p_s[4][16 * PST];

    const int tid = threadIdx.x;
    const int wave = tid >> 6, lane = tid & 63;
    const int quad = lane >> 4, l16 = lane & 15;
    const int q0 = blockIdx.x * 64;
    const int h = blockIdx.y, b = blockIdx.z;
    const size_t tokb = (size_t)b * S_;
    const size_t hoff = (size_t)h * HD_;

    const short* qg = Q + (tokb + q0) * 2048 + hoff;
    const short* kg = K + tokb * 2048 + hoff;
    const short* vg = V + tokb * 2048 + hoff;

    // stage Q tile 64 x 128 bf16
    {
        const int row = tid >> 2, c0 = (tid & 3) * 32;
        const short* src = qg + (size_t)row * 2048 + c0;
        short* dst = &q_s[row * QST + c0];
#pragma unroll
        for (int j = 0; j < 4; j++)
            *(int4*)&dst[j * 8] = *(const int4*)&src[j * 8];
    }
    __syncthreads();

    bfrag8 aq[4];
#pragma unroll
    for (int kb = 0; kb < 4; kb++)
        aq[kb] = *(const bfrag8*)&q_s[(wave * 16 + l16) * QST + kb * 32 + quad * 8];

    const float slope = exp2f(-0.5f * (float)(h + 1));
    float m_i[4] = {-INFINITY, -INFINITY, -INFINITY, -INFINITY};
    float l_i[4] = {0.f, 0.f, 0.f, 0.f};
    f32x4 o[8];
#pragma unroll
    for (int t = 0; t < 8; t++) o[t] = (f32x4){0.f, 0.f, 0.f, 0.f};

    const int q_pos0 = q0 + wave * 16 + quad * 4;
    const int nch = q0 / 32 + 2;
    const int kslot = ((tid >> 3) + (tid & 3) * 8) & 31;

    for (int ch = 0; ch < nch; ch++) {
        const int k0 = ch * 32;
        {
            const int row = tid >> 3, c0 = (tid & 7) * 16;
            const short* ks = kg + (size_t)(k0 + row) * 2048 + c0;
            *(int4*)&k_s[row * KST + c0]     = *(const int4*)&ks[0];
            *(int4*)&k_s[row * KST + c0 + 8] = *(const int4*)&ks[8];
            const short* vs = vg + (size_t)(k0 + row) * 2048 + c0;
            short tmp[16];
            *(int4*)&tmp[0] = *(const int4*)&vs[0];
            *(int4*)&tmp[8] = *(const int4*)&vs[8];
#pragma unroll
            for (int j = 0; j < 16; j++)
                vt_s[(c0 + j) * VST + kslot] = tmp[j];
        }
        __syncthreads();

        f32x4 sc[2];
#pragma unroll
        for (int t = 0; t < 2; t++) {
            sc[t] = (f32x4){0.f, 0.f, 0.f, 0.f};
#pragma unroll
            for (int kb = 0; kb < 4; kb++) {
                bfrag8 bk = *(const bfrag8*)&k_s[(t * 16 + l16) * KST + kb * 32 + quad * 8];
                sc[t] = __builtin_amdgcn_mfma_f32_16x16x32_bf16(aq[kb], bk, sc[t], 0, 0, 0);
            }
        }

#pragma unroll
        for (int r = 0; r < 4; r++) {
            const int q_pos = q_pos0 + r;
            const int kp0 = k0 + l16, kp1 = k0 + 16 + l16;
            float s0 = sc[0][r] * SCALE + slope * (float)(kp0 - q_pos);
            float s1 = sc[1][r] * SCALE + slope * (float)(kp1 - q_pos);
            if (kp0 > q_pos) s0 = -INFINITY;
            if (kp1 > q_pos) s1 = -INFINITY;
            float m = fmaxf(s0, s1);
#pragma unroll
            for (int off = 8; off >= 1; off >>= 1) m = fmaxf(m, __shfl_xor(m, off));
            const float m_new = fmaxf(m_i[r], m);
            const float alpha = __expf(m_i[r] - m_new);
            m_i[r] = m_new;
            const float p0 = __expf(s0 - m_new);
            const float p1 = __expf(s1 - m_new);
            float rsum = p0 + p1;
#pragma unroll
            for (int off = 8; off >= 1; off >>= 1) rsum += __shfl_xor(rsum, off);
            l_i[r] = l_i[r] * alpha + rsum;
#pragma unroll
            for (int t = 0; t < 8; t++) o[t][r] *= alpha;
            const int qr = quad * 4 + r;
            p_s[wave][qr * PST + l16]      = f2bf(p0);
            p_s[wave][qr * PST + 16 + l16] = f2bf(p1);
        }

        bfrag8 pa = *(const bfrag8*)&p_s[wave][l16 * PST + quad * 8];
#pragma unroll
        for (int t8 = 0; t8 < 8; t8++) {
            bfrag8 bv = *(const bfrag8*)&vt_s[(t8 * 16 + l16) * VST + ((quad + t8) & 3) * 8];
            o[t8] = __builtin_amdgcn_mfma_f32_16x16x32_bf16(pa, bv, o[t8], 0, 0, 0);
        }
        __syncthreads();
    }

    float inv[4];
#pragma unroll
    for (int r = 0; r < 4; r++) inv[r] = 1.0f / l_i[r];
    const size_t obase = (tokb + q0 + wave * 16 + quad * 4) * 2048 + hoff;
#pragma unroll
    for (int t8 = 0; t8 < 8; t8++)
#pragma unroll
        for (int r = 0; r < 4; r++) {
            float val = o[t8][r] * inv[r];
            short hi = f2bf(val);
            short lo = f2bf(val - bf2f(hi));
            Oh[obase + (size_t)r * 2048 + t8 * 16 + l16] = hi;
            Ol[obase + (size_t)r * 2048 + t8 * 16 + l16] = lo;
        }
}

// ---------------------------------------------------------------------------
extern "C" void kernel_launch(void* const* d_in, const int* in_sizes, int n_in,
                              void* d_out, int out_size, void* d_ws, size_t ws_size,
                              hipStream_t stream) {
    const float* x    = (const float*)d_in[0];
    const float* xt   = (const float*)d_in[1];
    const float* wq   = (const float*)d_in[2];
    const float* wka  = (const float*)d_in[3];
    const float* knw  = (const float*)d_in[4];
    const float* wkb  = (const float*)d_in[5];
    const float* kron = (const float*)d_in[6];
    const float* wo   = (const float*)d_in[7];
    float* out = (float*)d_out;

    const int M = B_ * S_; // 4096
    char* base = (char*)d_ws;
    short* x_bf   = (short*)(base);              // 16777216 B
    float* kc     = (float*)(base + 16777216);   //  8388608 B
    short* kc_bf  = (short*)(base + 25165824);   //  4194304 B
    short* wq_bf  = (short*)(base + 29360128);   //  8388608 B
    short* wka_bf = (short*)(base + 37748736);   //  2097152 B
    short* wkb_bf = (short*)(base + 39845888);   //  2097152 B
    short* wo_hi  = (short*)(base + 41943040);   //  8388608 B
    short* wo_lo  = (short*)(base + 50331648);   //  8388608 B
    short* q_bf   = (short*)(base + 58720256);   // 16777216 B
    short* k_bf   = (short*)(base + 75497472);   // 16777216 B
    short* v_bf   = (short*)(base + 92274688);   // 16777216 B -> end 109051904
    // att reuses regions dead by flash time:
    short* att_hi = x_bf;                        // over x_bf
    short* att_lo = (short*)(base + 16777216);   // over kc/kc_bf/wq_bf (dead)

    // convert inputs to bf16
    cvt_bf16<<<8388608 / 2048, 256, 0, stream>>>(x, x_bf);
    cvt_bf16<<<4194304 / 2048, 256, 0, stream>>>(wq, wq_bf);
    cvt_bf16<<<1048576 / 2048, 256, 0, stream>>>(wka, wka_bf);
    cvt_bf16<<<1048576 / 2048, 256, 0, stream>>>(wkb, wkb_bf);
    cvt_split<<<4194304 / 2048, 256, 0, stream>>>(wo, wo_hi, wo_lo);

    // Q = x @ wq^T (bf16 out)
    gemm_bf16<1><<<dim3(2048 / 128, M / 128), 256, 0, stream>>>(x_bf, wq_bf, nullptr, q_bf, M, 2048, 2048);
    // kc = x @ wka^T (fp32 out), RMSNorm -> bf16
    gemm_bf16<0><<<dim3(512 / 128, M / 128), 256, 0, stream>>>(x_bf, wka_bf, kc, nullptr, M, 512, 2048);
    rmsnorm_bf16<<<M, 256, 0, stream>>>(kc, knw, kc_bf);
    // K = kc @ wkb^T (bf16 out)
    gemm_bf16<1><<<dim3(2048 / 128, M / 128), 256, 0, stream>>>(kc_bf, wkb_bf, nullptr, k_bf, M, 2048, 512);
    // V head-mix (bf16 out)
    vmix_kernel<<<M, 256, 0, stream>>>(xt, kron, v_bf);
    // attention -> att_hi/att_lo
    flash_mfma<<<dim3(S_ / 64, H_, B_), 256, 0, stream>>>(q_bf, k_bf, v_bf, att_hi, att_lo);
    // out = att @ wo^T, split 3-pass for ~fp32 precision
    gemm_split3<<<dim3(2048 / 128, M / 128), 256, 0, stream>>>(att_hi, att_lo, wo_hi, wo_lo, out, M, 2048, 2048);
}

// Round 4
// 494.221 us; speedup vs baseline: 5.8006x; 1.2137x over previous
//
#include <hip/hip_runtime.h>
#include <math.h>

// Problem constants
constexpr int B_ = 2, S_ = 2048, H_ = 16, HD_ = 128, RANK_ = 512;
constexpr float EPS = 1e-6f;
constexpr float SCALE = 0.08838834764831845f; // 1/sqrt(128)
constexpr float M0 = 12.0f; // static softmax max bound (qk*SCALE ~ N(0,1), extreme ~6)

typedef __attribute__((ext_vector_type(8))) short bfrag8; // 8 bf16 (4 VGPRs)
typedef __attribute__((ext_vector_type(4))) float f32x4;  // MFMA C/D

static __device__ __forceinline__ short f2bf(float f) {
    union { float f; unsigned u; } v; v.f = f;
    unsigned r = v.u + 0x7fffu + ((v.u >> 16) & 1u); // RNE
    return (short)(r >> 16);
}
static __device__ __forceinline__ float bf2f(short h) {
    union { unsigned u; float f; } v;
    v.u = ((unsigned)(unsigned short)h) << 16;
    return v.f;
}

typedef __attribute__((address_space(1))) void gvoid_t;
typedef __attribute__((address_space(3))) void lvoid_t;
static __device__ __forceinline__ void gll16(const short* g, short* l) {
    __builtin_amdgcn_global_load_lds((const gvoid_t*)g, (lvoid_t*)l, 16, 0, 0);
}

// ---------------------------------------------------------------------------
// fp32 -> bf16 convert
// ---------------------------------------------------------------------------
__global__ __launch_bounds__(256) void cvt_bf16(const float* __restrict__ in,
                                                short* __restrict__ out) {
    const int i = (blockIdx.x * 256 + threadIdx.x) * 8;
    float4 f0 = *(const float4*)&in[i];
    float4 f1 = *(const float4*)&in[i + 4];
    short s[8] = {f2bf(f0.x), f2bf(f0.y), f2bf(f0.z), f2bf(f0.w),
                  f2bf(f1.x), f2bf(f1.y), f2bf(f1.z), f2bf(f1.w)};
    *(int4*)&out[i] = *(const int4*)s;
}

// fp32 -> (hi, lo) bf16 split
__global__ __launch_bounds__(256) void cvt_split(const float* __restrict__ in,
                                                 short* __restrict__ hi,
                                                 short* __restrict__ lo) {
    const int i = (blockIdx.x * 256 + threadIdx.x) * 8;
    float f[8];
    *(float4*)&f[0] = *(const float4*)&in[i];
    *(float4*)&f[4] = *(const float4*)&in[i + 4];
    short h[8], l[8];
#pragma unroll
    for (int k = 0; k < 8; k++) {
        h[k] = f2bf(f[k]);
        l[k] = f2bf(f[k] - bf2f(h[k]));
    }
    *(int4*)&hi[i] = *(const int4*)h;
    *(int4*)&lo[i] = *(const int4*)l;
}

// ---------------------------------------------------------------------------
// bf16 MFMA GEMM (m97 structure): C[M,N] = A[M,K] @ W[N,K]^T
// ---------------------------------------------------------------------------
template <int OUTBF>
__global__ __launch_bounds__(256)
void gemm_bf16(const short* __restrict__ A, const short* __restrict__ W,
               float* __restrict__ Cf, short* __restrict__ Cb,
               int M, int N, int K) {
    __shared__ short As[128 * 32];
    __shared__ short Bs[128 * 32];
    const int tid = threadIdx.x;
    const int wave = tid >> 6, lane = tid & 63;
    const int quad = lane >> 4, l16 = lane & 15;
    const int wm = (wave & 1) * 64, wn = (wave >> 1) * 64;
    const int m0 = blockIdx.y * 128, n0 = blockIdx.x * 128;

    const int srow = wave * 32 + (lane >> 2);
    const int scol = (lane & 3) * 8;
    const short* ag0 = A + (size_t)(m0 + srow) * K + scol;
    const short* ag1 = A + (size_t)(m0 + srow + 16) * K + scol;
    const short* bg0 = W + (size_t)(n0 + srow) * K + scol;
    const short* bg1 = W + (size_t)(n0 + srow + 16) * K + scol;
    short* al0 = &As[(wave * 32) * 32];
    short* al1 = &As[(wave * 32 + 16) * 32];
    short* bl0 = &Bs[(wave * 32) * 32];
    short* bl1 = &Bs[(wave * 32 + 16) * 32];

    f32x4 acc[4][4];
#pragma unroll
    for (int i = 0; i < 4; i++)
#pragma unroll
        for (int j = 0; j < 4; j++) acc[i][j] = (f32x4){0.f, 0.f, 0.f, 0.f};

    for (int k0 = 0; k0 < K; k0 += 32) {
        gll16(ag0 + k0, al0);
        gll16(ag1 + k0, al1);
        gll16(bg0 + k0, bl0);
        gll16(bg1 + k0, bl1);
        __syncthreads();
        bfrag8 af[4], bf[4];
#pragma unroll
        for (int i = 0; i < 4; i++)
            af[i] = *(const bfrag8*)&As[(wm + i * 16 + l16) * 32 + quad * 8];
#pragma unroll
        for (int j = 0; j < 4; j++)
            bf[j] = *(const bfrag8*)&Bs[(wn + j * 16 + l16) * 32 + quad * 8];
#pragma unroll
        for (int i = 0; i < 4; i++)
#pragma unroll
            for (int j = 0; j < 4; j++)
                acc[i][j] = __builtin_amdgcn_mfma_f32_16x16x32_bf16(af[i], bf[j], acc[i][j], 0, 0, 0);
        __syncthreads();
    }

#pragma unroll
    for (int i = 0; i < 4; i++)
#pragma unroll
        for (int j = 0; j < 4; j++) {
            const size_t rbase = (size_t)(m0 + wm + i * 16 + quad * 4);
            const int col = n0 + wn + j * 16 + l16;
#pragma unroll
            for (int r = 0; r < 4; r++) {
                if (OUTBF) Cb[(rbase + r) * N + col] = f2bf(acc[i][j][r]);
                else       Cf[(rbase + r) * N + col] = acc[i][j][r];
            }
        }
}

// ---------------------------------------------------------------------------
// split hi/lo 3-pass bf16 GEMM
// ---------------------------------------------------------------------------
__global__ __launch_bounds__(256)
void gemm_split3(const short* __restrict__ Ah, const short* __restrict__ Al,
                 const short* __restrict__ Wh, const short* __restrict__ Wl,
                 float* __restrict__ C, int M, int N, int K) {
    __shared__ short AsH[128 * 32], AsL[128 * 32];
    __shared__ short BsH[128 * 32], BsL[128 * 32];
    const int tid = threadIdx.x;
    const int wave = tid >> 6, lane = tid & 63;
    const int quad = lane >> 4, l16 = lane & 15;
    const int wm = (wave & 1) * 64, wn = (wave >> 1) * 64;
    const int m0 = blockIdx.y * 128, n0 = blockIdx.x * 128;

    const int srow = wave * 32 + (lane >> 2);
    const int scol = (lane & 3) * 8;
    const size_t aoff0 = (size_t)(m0 + srow) * K + scol;
    const size_t aoff1 = (size_t)(m0 + srow + 16) * K + scol;
    const size_t boff0 = (size_t)(n0 + srow) * K + scol;
    const size_t boff1 = (size_t)(n0 + srow + 16) * K + scol;
    const int lb0 = (wave * 32) * 32, lb1 = (wave * 32 + 16) * 32;

    f32x4 acc[4][4];
#pragma unroll
    for (int i = 0; i < 4; i++)
#pragma unroll
        for (int j = 0; j < 4; j++) acc[i][j] = (f32x4){0.f, 0.f, 0.f, 0.f};

    for (int k0 = 0; k0 < K; k0 += 32) {
        gll16(Ah + aoff0 + k0, &AsH[lb0]);
        gll16(Ah + aoff1 + k0, &AsH[lb1]);
        gll16(Al + aoff0 + k0, &AsL[lb0]);
        gll16(Al + aoff1 + k0, &AsL[lb1]);
        gll16(Wh + boff0 + k0, &BsH[lb0]);
        gll16(Wh + boff1 + k0, &BsH[lb1]);
        gll16(Wl + boff0 + k0, &BsL[lb0]);
        gll16(Wl + boff1 + k0, &BsL[lb1]);
        __syncthreads();
        bfrag8 fah[4], fal[4], fbh[4], fbl[4];
#pragma unroll
        for (int i = 0; i < 4; i++) {
            const int ro = (wm + i * 16 + l16) * 32 + quad * 8;
            fah[i] = *(const bfrag8*)&AsH[ro];
            fal[i] = *(const bfrag8*)&AsL[ro];
        }
#pragma unroll
        for (int j = 0; j < 4; j++) {
            const int ro = (wn + j * 16 + l16) * 32 + quad * 8;
            fbh[j] = *(const bfrag8*)&BsH[ro];
            fbl[j] = *(const bfrag8*)&BsL[ro];
        }
#pragma unroll
        for (int i = 0; i < 4; i++)
#pragma unroll
            for (int j = 0; j < 4; j++) {
                acc[i][j] = __builtin_amdgcn_mfma_f32_16x16x32_bf16(fah[i], fbh[j], acc[i][j], 0, 0, 0);
                acc[i][j] = __builtin_amdgcn_mfma_f32_16x16x32_bf16(fah[i], fbl[j], acc[i][j], 0, 0, 0);
                acc[i][j] = __builtin_amdgcn_mfma_f32_16x16x32_bf16(fal[i], fbh[j], acc[i][j], 0, 0, 0);
            }
        __syncthreads();
    }

#pragma unroll
    for (int i = 0; i < 4; i++)
#pragma unroll
        for (int j = 0; j < 4; j++) {
            const size_t rbase = (size_t)(m0 + wm + i * 16 + quad * 4);
            const int col = n0 + wn + j * 16 + l16;
#pragma unroll
            for (int r = 0; r < 4; r++)
                C[(rbase + r) * N + col] = acc[i][j][r];
        }
}

// ---------------------------------------------------------------------------
// RMSNorm rows of 512: fp32 in -> bf16 out
// ---------------------------------------------------------------------------
__global__ __launch_bounds__(256) void rmsnorm_bf16(const float* __restrict__ X,
                                                    const float* __restrict__ w,
                                                    short* __restrict__ Y) {
    const int row = blockIdx.x;
    const float* x = X + (size_t)row * RANK_;
    const int t = threadIdx.x;
    float v0 = x[t], v1 = x[t + 256];
    float ss = v0 * v0 + v1 * v1;
#pragma unroll
    for (int off = 32; off; off >>= 1) ss += __shfl_down(ss, off);
    __shared__ float red[4];
    if ((t & 63) == 0) red[t >> 6] = ss;
    __syncthreads();
    float tot = red[0] + red[1] + red[2] + red[3];
    float rs = rsqrtf(tot * (1.0f / RANK_) + EPS);
    short* y = Y + (size_t)row * RANK_;
    y[t]       = f2bf(v0 * rs * w[t]);
    y[t + 256] = f2bf(v1 * rs * w[t + 256]);
}

// ---------------------------------------------------------------------------
// V head-mix -> bf16 (row-major [token][h*128+d])
// ---------------------------------------------------------------------------
__global__ __launch_bounds__(256) void vmix_kernel(const float* __restrict__ xt,
                                                   const float* __restrict__ kron,
                                                   short* __restrict__ V) {
    __shared__ float xr[2048];
    __shared__ float kr[256];
    const int bs = blockIdx.x;
    const float* x = xt + (size_t)bs * 2048;
    const int t = threadIdx.x;
    kr[t] = kron[t];
#pragma unroll
    for (int it = 0; it < 8; it++) xr[t + it * 256] = x[t + it * 256];
    __syncthreads();
    const int d = t & 127;
    const int i0 = (t >> 7) * 8;
    float acc[8] = {};
#pragma unroll
    for (int j = 0; j < 16; j++) {
        float xv = xr[j * 128 + d];
#pragma unroll
        for (int ii = 0; ii < 8; ii++) acc[ii] += kr[(i0 + ii) * 16 + j] * xv;
    }
    short* out = V + (size_t)bs * 2048;
#pragma unroll
    for (int ii = 0; ii < 8; ii++) out[(i0 + ii) * 128 + d] = f2bf(acc[ii]);
}

// ---------------------------------------------------------------------------
// Transpose V: [b*S + s][h*128 + d] -> Vt[(b*16+h)*128 + d][s]
// Block: 64 tokens x 128 d for one (b,h). Grid (S/64, H, B).
// ---------------------------------------------------------------------------
__global__ __launch_bounds__(256) void transpose_v(const short* __restrict__ V,
                                                   short* __restrict__ Vt) {
    __shared__ short tile[64 * 136];
    const int s0 = blockIdx.x * 64, h = blockIdx.y, b = blockIdx.z;
    const int tid = threadIdx.x;
    {
        const int tok = tid >> 2, c = (tid & 3) * 32;
        const short* src = V + ((size_t)(b * S_ + s0 + tok)) * 2048 + h * 128 + c;
        short* dst = &tile[tok * 136 + c];
#pragma unroll
        for (int j = 0; j < 4; j++)
            *(int4*)&dst[j * 8] = *(const int4*)&src[j * 8];
    }
    __syncthreads();
    {
        const int d = tid >> 1, th = tid & 1;
        short buf[32];
#pragma unroll
        for (int j = 0; j < 32; j++)
            buf[j] = tile[(th * 32 + j) * 136 + d];
        short* dst = Vt + ((size_t)((b * 16 + h) * 128 + d)) * S_ + s0 + th * 32;
#pragma unroll
        for (int j = 0; j < 4; j++)
            *(int4*)&dst[j * 8] = *(const int4*)&buf[j * 8];
    }
}

// ---------------------------------------------------------------------------
// MFMA flash attention v2: fixed-max softmax (no shfl, no rescale),
// l via ones-column MFMA, pre-transposed V, ALiBi head windowing.
// Block = 4 waves, BQ=64 (16 q-rows/wave), BK=32.
// ---------------------------------------------------------------------------
constexpr int QST = 128;
constexpr int KST = 136;
constexpr int VST = 40;
constexpr int PST = 40;

__global__ __launch_bounds__(256, 4)
void flash_mfma(const short* __restrict__ Q, const short* __restrict__ K,
                const short* __restrict__ Vt, short* __restrict__ Oh,
                short* __restrict__ Ol) {
    __shared__ __align__(16) short q_s[64 * QST];   // 16384 B
    __shared__ __align__(16) short k_s[32 * KST];   //  8704 B
    __shared__ __align__(16) short vt_s[128 * VST]; // 10240 B
    __shared__ __align__(16) short p_s[4][16 * PST];//  5120 B => 40448 B

    const int tid = threadIdx.x;
    const int wave = tid >> 6, lane = tid & 63;
    const int quad = lane >> 4, l16 = lane & 15;
    const int q0 = blockIdx.x * 64;
    const int h = blockIdx.y, b = blockIdx.z;
    const size_t tokb = (size_t)b * S_;
    const size_t hoff = (size_t)h * HD_;

    const short* qg = Q + (tokb + q0) * 2048 + hoff;
    const short* kg = K + tokb * 2048 + hoff;
    const short* vtg = Vt + ((size_t)(b * 16 + h) * 128) * S_; // [d][token]

    // stage Q tile 64 x 128
    {
        const int row = tid >> 2, c0 = (tid & 3) * 32;
        const short* src = qg + (size_t)row * 2048 + c0;
        short* dst = &q_s[row * QST + c0];
#pragma unroll
        for (int j = 0; j < 4; j++)
            *(int4*)&dst[j * 8] = *(const int4*)&src[j * 8];
    }
    __syncthreads();

    bfrag8 aq[4];
#pragma unroll
    for (int kb = 0; kb < 4; kb++)
        aq[kb] = *(const bfrag8*)&q_s[(wave * 16 + l16) * QST + kb * 32 + quad * 8];

    bfrag8 bones;
#pragma unroll
    for (int i = 0; i < 8; i++) bones[i] = (short)0x3F80; // bf16 1.0

    const float slope = exp2f(-0.5f * (float)(h + 1));
    f32x4 lacc = (f32x4){0.f, 0.f, 0.f, 0.f};
    f32x4 o[8];
#pragma unroll
    for (int t = 0; t < 8; t++) o[t] = (f32x4){0.f, 0.f, 0.f, 0.f};

    const int q_pos0 = q0 + wave * 16 + quad * 4;
    const int nch = q0 / 32 + 2;
    // ALiBi window: keys farther than W have relative weight < e^-28 -> skip
    const int Wi = (int)(40.0f * exp2f(0.5f * (float)(h + 1)));
    const int csd = q0 - Wi;
    const int ch_start = csd > 0 ? (csd >> 5) : 0;

    for (int ch = ch_start; ch < nch; ch++) {
        const int k0 = ch * 32;
        // stage K (row-major) + Vt (d-major, 2 b128 writes each)
        {
            const int row = tid >> 3, c0 = (tid & 7) * 16;
            const short* ks = kg + (size_t)(k0 + row) * 2048 + c0;
            *(int4*)&k_s[row * KST + c0]     = *(const int4*)&ks[0];
            *(int4*)&k_s[row * KST + c0 + 8] = *(const int4*)&ks[8];
            const int d = tid >> 1, kh = tid & 1;
            const short* vs = vtg + (size_t)d * S_ + k0 + kh * 16;
            *(int4*)&vt_s[d * VST + kh * 16]     = *(const int4*)&vs[0];
            *(int4*)&vt_s[d * VST + kh * 16 + 8] = *(const int4*)&vs[8];
        }
        __syncthreads();

        // QK^T: S[16q x 32keys]
        f32x4 sc[2];
#pragma unroll
        for (int t = 0; t < 2; t++) {
            sc[t] = (f32x4){0.f, 0.f, 0.f, 0.f};
#pragma unroll
            for (int kb = 0; kb < 4; kb++) {
                bfrag8 bk = *(const bfrag8*)&k_s[(t * 16 + l16) * KST + kb * 32 + quad * 8];
                sc[t] = __builtin_amdgcn_mfma_f32_16x16x32_bf16(aq[kb], bk, sc[t], 0, 0, 0);
            }
        }

        // fixed-max softmax: p = exp(s - M0); no reductions, no rescale
        const int kp0 = k0 + l16, kp1 = k0 + 16 + l16;
#pragma unroll
        for (int r = 0; r < 4; r++) {
            const int q_pos = q_pos0 + r;
            float s0 = sc[0][r] * SCALE + slope * (float)(kp0 - q_pos) - M0;
            float s1 = sc[1][r] * SCALE + slope * (float)(kp1 - q_pos) - M0;
            if (kp0 > q_pos) s0 = -1e30f;
            if (kp1 > q_pos) s1 = -1e30f;
            const int qr = quad * 4 + r;
            p_s[wave][qr * PST + l16]      = f2bf(__expf(s0));
            p_s[wave][qr * PST + 16 + l16] = f2bf(__expf(s1));
        }

        // PV + l (ones column). p_s wave-private: DS in-order, no barrier.
        bfrag8 pa = *(const bfrag8*)&p_s[wave][l16 * PST + quad * 8];
        lacc = __builtin_amdgcn_mfma_f32_16x16x32_bf16(pa, bones, lacc, 0, 0, 0);
#pragma unroll
        for (int t8 = 0; t8 < 8; t8++) {
            bfrag8 bv = *(const bfrag8*)&vt_s[(t8 * 16 + l16) * VST + quad * 8];
            o[t8] = __builtin_amdgcn_mfma_f32_16x16x32_bf16(pa, bv, o[t8], 0, 0, 0);
        }
        __syncthreads();
    }

    float inv[4];
#pragma unroll
    for (int r = 0; r < 4; r++) inv[r] = 1.0f / lacc[r];
    const size_t obase = (tokb + q0 + wave * 16 + quad * 4) * 2048 + hoff;
#pragma unroll
    for (int t8 = 0; t8 < 8; t8++)
#pragma unroll
        for (int r = 0; r < 4; r++) {
            float val = o[t8][r] * inv[r];
            short hi = f2bf(val);
            short lo = f2bf(val - bf2f(hi));
            Oh[obase + (size_t)r * 2048 + t8 * 16 + l16] = hi;
            Ol[obase + (size_t)r * 2048 + t8 * 16 + l16] = lo;
        }
}

// ---------------------------------------------------------------------------
extern "C" void kernel_launch(void* const* d_in, const int* in_sizes, int n_in,
                              void* d_out, int out_size, void* d_ws, size_t ws_size,
                              hipStream_t stream) {
    const float* x    = (const float*)d_in[0];
    const float* xt   = (const float*)d_in[1];
    const float* wq   = (const float*)d_in[2];
    const float* wka  = (const float*)d_in[3];
    const float* knw  = (const float*)d_in[4];
    const float* wkb  = (const float*)d_in[5];
    const float* kron = (const float*)d_in[6];
    const float* wo   = (const float*)d_in[7];
    float* out = (float*)d_out;

    const int M = B_ * S_; // 4096
    char* base = (char*)d_ws;
    short* x_bf   = (short*)(base);              // 16 MB
    float* kc     = (float*)(base + 16777216);   //  8 MB
    short* kc_bf  = (short*)(base + 25165824);   //  4 MB
    short* wq_bf  = (short*)(base + 29360128);   //  8 MB
    short* wka_bf = (short*)(base + 37748736);   //  2 MB
    short* wkb_bf = (short*)(base + 39845888);   //  2 MB
    short* wo_hi  = (short*)(base + 41943040);   //  8 MB
    short* wo_lo  = (short*)(base + 50331648);   //  8 MB
    short* q_bf   = (short*)(base + 58720256);   // 16 MB
    short* k_bf   = (short*)(base + 75497472);   // 16 MB
    short* v_bf   = (short*)(base + 92274688);   // 16 MB
    short* vt_bf  = (short*)(base + 109051904);  // 16 MB -> end 125829120
    short* att_hi = x_bf;                        // x_bf dead by flash time
    short* att_lo = (short*)(base + 16777216);   // kc/kc_bf/wq_bf dead

    cvt_bf16<<<8388608 / 2048, 256, 0, stream>>>(x, x_bf);
    cvt_bf16<<<4194304 / 2048, 256, 0, stream>>>(wq, wq_bf);
    cvt_bf16<<<1048576 / 2048, 256, 0, stream>>>(wka, wka_bf);
    cvt_bf16<<<1048576 / 2048, 256, 0, stream>>>(wkb, wkb_bf);
    cvt_split<<<4194304 / 2048, 256, 0, stream>>>(wo, wo_hi, wo_lo);

    gemm_bf16<1><<<dim3(2048 / 128, M / 128), 256, 0, stream>>>(x_bf, wq_bf, nullptr, q_bf, M, 2048, 2048);
    gemm_bf16<0><<<dim3(512 / 128, M / 128), 256, 0, stream>>>(x_bf, wka_bf, kc, nullptr, M, 512, 2048);
    rmsnorm_bf16<<<M, 256, 0, stream>>>(kc, knw, kc_bf);
    gemm_bf16<1><<<dim3(2048 / 128, M / 128), 256, 0, stream>>>(kc_bf, wkb_bf, nullptr, k_bf, M, 2048, 512);
    vmix_kernel<<<M, 256, 0, stream>>>(xt, kron, v_bf);
    transpose_v<<<dim3(S_ / 64, H_, B_), 256, 0, stream>>>(v_bf, vt_bf);
    flash_mfma<<<dim3(S_ / 64, H_, B_), 256, 0, stream>>>(q_bf, k_bf, vt_bf, att_hi, att_lo);
    gemm_split3<<<dim3(2048 / 128, M / 128), 256, 0, stream>>>(att_hi, att_lo, wo_hi, wo_lo, out, M, 2048, 2048);
}